// Round 15
// baseline (1214.249 us; speedup 1.0000x reference)
//
#include <hip/hip_runtime.h>
#include <hip/hip_bf16.h>

#define DD 512
#define BM 32
#define TILES 32          // rows per block = BM*TILES = 1024
#define THREADS 1024

typedef __attribute__((ext_vector_type(8))) short short8;   // 8 bf16 = 4 VGPRs (MFMA A/B frag)
typedef __attribute__((ext_vector_type(4))) float f32x4;    // MFMA C/D frag

__device__ __forceinline__ unsigned short f2bf(float f) {
  union { float f; unsigned u; } v; v.f = f;
  unsigned r = v.u + 0x7FFFu + ((v.u >> 16) & 1u);  // RNE
  return (unsigned short)(r >> 16);
}
__device__ __forceinline__ float bf2f(unsigned short u) {
  union { unsigned u; float f; } v; v.u = ((unsigned)u) << 16;
  return v.f;
}

// Pack kernel (K x N fp32, row-major) into MFMA-fragment-major bf16:
//   Bpack[((nb*16 + kt)*64 + lane)*8 + j]  holds  B[k][n]
//   with n = nb*16 + (lane&15), k = kt*32 + (lane>>4)*8 + j.
__global__ void prep_bpack(const float* __restrict__ W, unsigned short* __restrict__ Bpack) {
  const int tid = blockIdx.x * blockDim.x + threadIdx.x;   // 262144 threads
  const int n = tid & 511, k = tid >> 9;
  const float w = W[(size_t)k * DD + n];                   // coalesced read
  const int nb = n >> 4, lo = n & 15;
  const int kt = k >> 5, hi = (k >> 3) & 3, j = k & 7;
  const int lane = hi * 16 + lo;
  Bpack[(((size_t)(nb * 16 + kt)) * 64 + lane) * 8 + j] = f2bf(w);
}

// Persistent producer/consumer fused kernel.
// Grid = 256 (1 block/CU). 16 waves: waves 0-7 = PRODUCERS (load x, LN+relu,
// write bf16 h and x into double-buffered LDS), waves 8-15 = CONSUMERS
// (GEMM from Alds vs Bpack with pinned depth-3 B ring, epilogue
// out = acc + x + bias). One lgkmcnt-only barrier per tile: producer HBM
// reads, consumer HBM stores, and L2 B-loads all overlap continuously.
__global__ __launch_bounds__(THREADS, 4)   // 16 waves, VGPR cap 128
void fused_ln_gemm(const float* __restrict__ x, const float* __restrict__ lns,
                   const float* __restrict__ lnb, const unsigned short* __restrict__ Bpack,
                   const float* __restrict__ bias, float* __restrict__ out) {
  __shared__ unsigned short Alds[2][BM * 512];   // 2 x 32 KB, h bf16, XOR-swizzled
  __shared__ unsigned short Xlds[2][BM * 512];   // 2 x 32 KB, x bf16, XOR-swizzled

  const int t = threadIdx.x;
  const long base = (long)blockIdx.x * (BM * TILES);
  const bool producer = (t < 512);

  if (producer) {
    // ================= PRODUCER: LN + relu into buf[(it+1)&1] ==========
    const int r = t >> 4, g = t & 15;          // 16 threads/row, 32 rows
    const unsigned abyte = (unsigned)(r * 1024 + g * 8) ^ (unsigned)((r & 7) << 4);

    // prologue: tile 0 -> buf 0
    #pragma unroll 1
    for (int it = -1; it + 1 < TILES; ++it) {
      const long trow = base + (long)(it + 1) * BM;
      const int buf = (it + 1) & 1;
      const float* xr = x + (trow + r) * DD + g * 4;
      float4 v[8];
      float s = 0.f, s2 = 0.f;
      #pragma unroll
      for (int i = 0; i < 8; ++i) {
        v[i] = *(const float4*)(xr + i * 64);
        s  += (v[i].x + v[i].y) + (v[i].z + v[i].w);
        s2 += v[i].x * v[i].x + v[i].y * v[i].y + v[i].z * v[i].z + v[i].w * v[i].w;
      }
      #pragma unroll
      for (int m = 1; m < 16; m <<= 1) {       // 16-lane group reduce
        s  += __shfl_xor(s,  m, 64);
        s2 += __shfl_xor(s2, m, 64);
      }
      const float mu   = s * (1.f / 512.f);
      const float var  = fmaxf(s2 * (1.f / 512.f) - mu * mu, 0.f);
      const float rstd = rsqrtf(var + 1e-6f);
      #pragma unroll
      for (int i = 0; i < 8; ++i) {
        const int c = g * 4 + i * 64;
        const float4 sc = *(const float4*)(lns + c);
        const float4 bi = *(const float4*)(lnb + c);
        ushort4 hu;
        hu.x = f2bf(fmaxf((v[i].x - mu) * rstd * sc.x + bi.x, 0.f));
        hu.y = f2bf(fmaxf((v[i].y - mu) * rstd * sc.y + bi.y, 0.f));
        hu.z = f2bf(fmaxf((v[i].z - mu) * rstd * sc.z + bi.z, 0.f));
        hu.w = f2bf(fmaxf((v[i].w - mu) * rstd * sc.w + bi.w, 0.f));
        ushort4 xu = { f2bf(v[i].x), f2bf(v[i].y), f2bf(v[i].z), f2bf(v[i].w) };
        const unsigned a = abyte ^ (unsigned)(i * 128);   // i*128 only touches bit7+
        *(ushort4*)((char*)&Alds[buf][0] + a) = hu;
        *(ushort4*)((char*)&Xlds[buf][0] + a) = xu;
      }
      asm volatile("s_waitcnt lgkmcnt(0)" ::: "memory");
      __builtin_amdgcn_s_barrier();
    }
    // final barrier of last iteration (consumers finish tile TILES-1)
    asm volatile("s_waitcnt lgkmcnt(0)" ::: "memory");
    __builtin_amdgcn_s_barrier();
  } else {
    // ================= CONSUMER: GEMM + epilogue on buf[it&1] ==========
    const int ci = t - 512;
    const int lane = ci & 63, lo = lane & 15, hi = lane >> 4;
    const int cw = ci >> 6;                    // 0..7 -> 64-col strip
    const int col0 = cw * 64 + lo;
    const float bv[4] = { bias[col0], bias[col0 + 16], bias[col0 + 32], bias[col0 + 48] };

    unsigned abase0 = (unsigned)(lo * 1024 + hi * 16);
    unsigned abase1 = (unsigned)((16 + lo) * 1024 + hi * 16);
    const unsigned asw = (unsigned)((lo & 7) << 4);
    // B frag (nb = cw*4 + nt, kt): Bpack8 + (nb*16 + kt)*64 + lane
    const short8* bbase = (const short8*)Bpack + (size_t)cw * 4096 + lane;

    // wait for producers' tile-0 LN
    __builtin_amdgcn_s_barrier();

    #pragma unroll 1
    for (int it = 0; it < TILES; ++it) {
      const long trow = base + (long)it * BM;
      const char* Ab = (const char*)&Alds[it & 1][0];
      const char* Xb = (const char*)&Xlds[it & 1][0];

      short8 rb[3][4];
#define LOADB(s_, kt)                                                        \
      { rb[s_][0] = bbase[(0 * 16 + (kt)) * 64];                             \
        rb[s_][1] = bbase[(1 * 16 + (kt)) * 64];                             \
        rb[s_][2] = bbase[(2 * 16 + (kt)) * 64];                             \
        rb[s_][3] = bbase[(3 * 16 + (kt)) * 64]; }

      LOADB(0, 0);
      LOADB(1, 1);
      __builtin_amdgcn_sched_barrier(0);

      f32x4 acc0[4] = {};
      f32x4 acc1[4] = {};
      #pragma unroll
      for (int kt = 0; kt < 16; ++kt) {
        const int cur = kt % 3;
        if (kt + 2 < 16) LOADB((kt + 2) % 3, kt + 2);
        __builtin_amdgcn_sched_barrier(0);
        const short8 a0 = *(const short8*)(Ab + ((abase0 + (unsigned)kt * 64) ^ asw));
        const short8 a1 = *(const short8*)(Ab + ((abase1 + (unsigned)kt * 64) ^ asw));
        #pragma unroll
        for (int nt = 0; nt < 4; ++nt) {
          acc0[nt] = __builtin_amdgcn_mfma_f32_16x16x32_bf16(a0, rb[cur][nt], acc0[nt], 0, 0, 0);
          acc1[nt] = __builtin_amdgcn_mfma_f32_16x16x32_bf16(a1, rb[cur][nt], acc1[nt], 0, 0, 0);
        }
      }
#undef LOADB

      // epilogue: out = acc + x(Xlds) + bias   (stores never drained)
      #pragma unroll
      for (int q = 0; q < 4; ++q) {
        {
          const int rl = hi * 4 + q;
          const unsigned xb = (unsigned)(rl * 1024 + col0 * 2) ^ (unsigned)((rl & 7) << 4);
          float* o = out + (trow + rl) * DD + col0;
          #pragma unroll
          for (int nt = 0; nt < 4; ++nt)   // +nt*16 cols = ^ (nt<<5): bits 5-6 clear in base
            o[nt * 16] = acc0[nt][q] + bf2f(*(const unsigned short*)(Xb + (xb ^ (unsigned)(nt << 5)))) + bv[nt];
        }
        {
          const int rl = 16 + hi * 4 + q;
          const unsigned xb = (unsigned)(rl * 1024 + col0 * 2) ^ (unsigned)((rl & 7) << 4);
          float* o = out + (trow + rl) * DD + col0;
          #pragma unroll
          for (int nt = 0; nt < 4; ++nt)
            o[nt * 16] = acc1[nt][q] + bf2f(*(const unsigned short*)(Xb + (xb ^ (unsigned)(nt << 5)))) + bv[nt];
        }
      }

      asm volatile("s_waitcnt lgkmcnt(0)" ::: "memory");
      __builtin_amdgcn_s_barrier();
    }
  }
}

extern "C" void kernel_launch(void* const* d_in, const int* in_sizes, int n_in,
                              void* d_out, int out_size, void* d_ws, size_t ws_size,
                              hipStream_t stream) {
  const float* x    = (const float*)d_in[0];
  const float* lns  = (const float*)d_in[1];
  const float* lnb  = (const float*)d_in[2];
  const float* W    = (const float*)d_in[3];
  const float* bias = (const float*)d_in[4];
  float* out = (float*)d_out;
  unsigned short* Bpack = (unsigned short*)d_ws;   // 512KB scratch

  const int nrows = in_sizes[0] / DD;

  prep_bpack<<<DD * DD / 256, 256, 0, stream>>>(W, Bpack);
  fused_ln_gemm<<<nrows / (BM * TILES), THREADS, 0, stream>>>(x, lns, lnb, Bpack, bias, out);
}

// Round 16
// 1160.037 us; speedup vs baseline: 1.0467x; 1.0467x over previous
//
#include <hip/hip_runtime.h>
#include <hip/hip_bf16.h>

#define DD 512
#define BM 32
#define TILES 32          // rows per block = BM*TILES = 1024
#define THREADS 1024

typedef __attribute__((ext_vector_type(8))) short short8;   // 8 bf16 = 4 VGPRs (MFMA A/B frag)
typedef __attribute__((ext_vector_type(4))) float f32x4;    // MFMA C/D frag

__device__ __forceinline__ unsigned short f2bf(float f) {
  union { float f; unsigned u; } v; v.f = f;
  unsigned r = v.u + 0x7FFFu + ((v.u >> 16) & 1u);  // RNE
  return (unsigned short)(r >> 16);
}
__device__ __forceinline__ float bf2f(unsigned short u) {
  union { unsigned u; float f; } v; v.u = ((unsigned)u) << 16;
  return v.f;
}

// Pack kernel (K x N fp32, row-major) into MFMA-fragment-major bf16:
//   Bpack[((nb*16 + kt)*64 + lane)*8 + j]  holds  B[k][n]
//   with n = nb*16 + (lane&15), k = kt*32 + (lane>>4)*8 + j.
__global__ void prep_bpack(const float* __restrict__ W, unsigned short* __restrict__ Bpack) {
  const int tid = blockIdx.x * blockDim.x + threadIdx.x;   // 262144 threads
  const int n = tid & 511, k = tid >> 9;
  const float w = W[(size_t)k * DD + n];                   // coalesced read
  const int nb = n >> 4, lo = n & 15;
  const int kt = k >> 5, hi = (k >> 3) & 3, j = k & 7;
  const int lane = hi * 16 + lo;
  Bpack[(((size_t)(nb * 16 + kt)) * 64 + lane) * 8 + j] = f2bf(w);
}

// Persistent producer/consumer fused kernel.
// Grid = 256 (1 block/CU). Waves 0-7 = PRODUCERS (load x, LN+relu, write bf16
// h and x into double-buffered LDS); waves 8-15 = CONSUMERS (GEMM vs Bpack
// with pinned depth-3 B ring, epilogue out = acc + x + bias). One
// lgkmcnt-only barrier per tile. amdgpu_waves_per_eu(4,4) pins the register
// budget to 128/wave so the consumer's ring+acc do NOT spill (R15's failure).
__global__ __launch_bounds__(THREADS)
__attribute__((amdgpu_waves_per_eu(4, 4)))
void fused_ln_gemm(const float* __restrict__ x, const float* __restrict__ lns,
                   const float* __restrict__ lnb, const unsigned short* __restrict__ Bpack,
                   const float* __restrict__ bias, float* __restrict__ out) {
  __shared__ unsigned short Alds[2][BM * 512];   // 2 x 32 KB, h bf16, XOR-swizzled
  __shared__ unsigned short Xlds[2][BM * 512];   // 2 x 32 KB, x bf16, XOR-swizzled

  const int t = threadIdx.x;
  const long base = (long)blockIdx.x * (BM * TILES);
  const bool producer = (t < 512);

  if (producer) {
    // ================= PRODUCER: LN + relu into buf[(it+1)&1] ==========
    const int r = t >> 4, g = t & 15;          // 16 threads/row, 32 rows
    const unsigned abyte = (unsigned)(r * 1024 + g * 8) ^ (unsigned)((r & 7) << 4);

    #pragma unroll 1
    for (int it = -1; it + 1 < TILES; ++it) {
      const long trow = base + (long)(it + 1) * BM;
      const int buf = (it + 1) & 1;
      const float* xr = x + (trow + r) * DD + g * 4;
      float4 v[8];
      float s = 0.f, s2 = 0.f;
      #pragma unroll
      for (int i = 0; i < 8; ++i) {
        v[i] = *(const float4*)(xr + i * 64);
        s  += (v[i].x + v[i].y) + (v[i].z + v[i].w);
        s2 += v[i].x * v[i].x + v[i].y * v[i].y + v[i].z * v[i].z + v[i].w * v[i].w;
      }
      #pragma unroll
      for (int m = 1; m < 16; m <<= 1) {       // 16-lane group reduce
        s  += __shfl_xor(s,  m, 64);
        s2 += __shfl_xor(s2, m, 64);
      }
      const float mu   = s * (1.f / 512.f);
      const float var  = fmaxf(s2 * (1.f / 512.f) - mu * mu, 0.f);
      const float rstd = rsqrtf(var + 1e-6f);
      #pragma unroll
      for (int i = 0; i < 8; ++i) {
        const int c = g * 4 + i * 64;
        const float4 sc = *(const float4*)(lns + c);
        const float4 bi = *(const float4*)(lnb + c);
        ushort4 hu;
        hu.x = f2bf(fmaxf((v[i].x - mu) * rstd * sc.x + bi.x, 0.f));
        hu.y = f2bf(fmaxf((v[i].y - mu) * rstd * sc.y + bi.y, 0.f));
        hu.z = f2bf(fmaxf((v[i].z - mu) * rstd * sc.z + bi.z, 0.f));
        hu.w = f2bf(fmaxf((v[i].w - mu) * rstd * sc.w + bi.w, 0.f));
        ushort4 xu = { f2bf(v[i].x), f2bf(v[i].y), f2bf(v[i].z), f2bf(v[i].w) };
        const unsigned a = abyte ^ (unsigned)(i * 128);   // i*128 only touches bit7+
        *(ushort4*)((char*)&Alds[buf][0] + a) = hu;
        *(ushort4*)((char*)&Xlds[buf][0] + a) = xu;
      }
      asm volatile("s_waitcnt lgkmcnt(0)" ::: "memory");
      __builtin_amdgcn_s_barrier();
    }
    // final barrier (consumers finish tile TILES-1)
    asm volatile("s_waitcnt lgkmcnt(0)" ::: "memory");
    __builtin_amdgcn_s_barrier();
  } else {
    // ================= CONSUMER: GEMM + epilogue on buf[it&1] ==========
    const int ci = t - 512;
    const int lane = ci & 63, lo = lane & 15, hi = lane >> 4;
    const int cw = ci >> 6;                    // 0..7 -> 64-col strip
    const int col0 = cw * 64 + lo;
    const float bv[4] = { bias[col0], bias[col0 + 16], bias[col0 + 32], bias[col0 + 48] };

    const unsigned abase0 = (unsigned)(lo * 1024 + hi * 16);
    const unsigned abase1 = (unsigned)((16 + lo) * 1024 + hi * 16);
    const unsigned asw = (unsigned)((lo & 7) << 4);
    // B frag (nb = cw*4 + nt, kt): Bpack8 + (nb*16 + kt)*64 + lane
    const short8* bbase = (const short8*)Bpack + (size_t)cw * 4096 + lane;

    short8 rb[3][4];
#define LOADB(s_, kt)                                                        \
    { rb[s_][0] = bbase[(0 * 16 + (kt)) * 64];                               \
      rb[s_][1] = bbase[(1 * 16 + (kt)) * 64];                               \
      rb[s_][2] = bbase[(2 * 16 + (kt)) * 64];                               \
      rb[s_][3] = bbase[(3 * 16 + (kt)) * 64]; }

    // prefetch tile-0's first ring slots BEFORE waiting for producers
    LOADB(0, 0);
    LOADB(1, 1);
    __builtin_amdgcn_sched_barrier(0);

    // wait for producers' tile-0 LN
    __builtin_amdgcn_s_barrier();

    #pragma unroll 1
    for (int it = 0; it < TILES; ++it) {
      const long trow = base + (long)it * BM;
      const char* Ab = (const char*)&Alds[it & 1][0];
      const char* Xb = (const char*)&Xlds[it & 1][0];

      f32x4 acc0[4] = {};
      f32x4 acc1[4] = {};
      #pragma unroll
      for (int kt = 0; kt < 16; ++kt) {
        const int cur = kt % 3;
        if (kt + 2 < 16) LOADB((kt + 2) % 3, kt + 2);
        __builtin_amdgcn_sched_barrier(0);
        const short8 a0 = *(const short8*)(Ab + ((abase0 + (unsigned)kt * 64) ^ asw));
        const short8 a1 = *(const short8*)(Ab + ((abase1 + (unsigned)kt * 64) ^ asw));
        #pragma unroll
        for (int nt = 0; nt < 4; ++nt) {
          acc0[nt] = __builtin_amdgcn_mfma_f32_16x16x32_bf16(a0, rb[cur][nt], acc0[nt], 0, 0, 0);
          acc1[nt] = __builtin_amdgcn_mfma_f32_16x16x32_bf16(a1, rb[cur][nt], acc1[nt], 0, 0, 0);
        }
      }

      // epilogue: out = acc + x(Xlds) + bias   (stores never drained)
      #pragma unroll
      for (int q = 0; q < 4; ++q) {
        {
          const int rl = hi * 4 + q;
          const unsigned xb = (unsigned)(rl * 1024 + col0 * 2) ^ (unsigned)((rl & 7) << 4);
          float* o = out + (trow + rl) * DD + col0;
          #pragma unroll
          for (int nt = 0; nt < 4; ++nt)   // +nt*16 cols = ^ (nt<<5): bits 5-6 clear in base
            o[nt * 16] = acc0[nt][q] + bf2f(*(const unsigned short*)(Xb + (xb ^ (unsigned)(nt << 5)))) + bv[nt];
        }
        {
          const int rl = 16 + hi * 4 + q;
          const unsigned xb = (unsigned)(rl * 1024 + col0 * 2) ^ (unsigned)((rl & 7) << 4);
          float* o = out + (trow + rl) * DD + col0;
          #pragma unroll
          for (int nt = 0; nt < 4; ++nt)
            o[nt * 16] = acc1[nt][q] + bf2f(*(const unsigned short*)(Xb + (xb ^ (unsigned)(nt << 5)))) + bv[nt];
        }
      }

      // prefetch NEXT tile's first ring slots (B is tile-independent)
      if (it + 1 < TILES) {
        LOADB(0, 0);
        LOADB(1, 1);
        __builtin_amdgcn_sched_barrier(0);
      }

      asm volatile("s_waitcnt lgkmcnt(0)" ::: "memory");
      __builtin_amdgcn_s_barrier();
    }
#undef LOADB
  }
}

extern "C" void kernel_launch(void* const* d_in, const int* in_sizes, int n_in,
                              void* d_out, int out_size, void* d_ws, size_t ws_size,
                              hipStream_t stream) {
  const float* x    = (const float*)d_in[0];
  const float* lns  = (const float*)d_in[1];
  const float* lnb  = (const float*)d_in[2];
  const float* W    = (const float*)d_in[3];
  const float* bias = (const float*)d_in[4];
  float* out = (float*)d_out;
  unsigned short* Bpack = (unsigned short*)d_ws;   // 512KB scratch

  const int nrows = in_sizes[0] / DD;

  prep_bpack<<<DD * DD / 256, 256, 0, stream>>>(W, Bpack);
  fused_ln_gemm<<<nrows / (BM * TILES), THREADS, 0, stream>>>(x, lns, lnb, Bpack, bias, out);
}

// Round 17
// 1113.422 us; speedup vs baseline: 1.0906x; 1.0419x over previous
//
#include <hip/hip_runtime.h>
#include <hip/hip_bf16.h>

#define DD 512
#define BM 32
#define TILES 32          // rows per block = BM*TILES = 1024
#define THREADS 1024

typedef __attribute__((ext_vector_type(8))) short short8;   // 8 bf16 = 4 VGPRs (MFMA A/B frag)
typedef __attribute__((ext_vector_type(4))) float f32x4;    // MFMA C/D frag

__device__ __forceinline__ unsigned short f2bf(float f) {
  union { float f; unsigned u; } v; v.f = f;
  unsigned r = v.u + 0x7FFFu + ((v.u >> 16) & 1u);  // RNE
  return (unsigned short)(r >> 16);
}
__device__ __forceinline__ float bf2f(unsigned short u) {
  union { unsigned u; float f; } v; v.u = ((unsigned)u) << 16;
  return v.f;
}

// Pack kernel (K x N fp32, row-major) into MFMA-fragment-major bf16:
//   Bpack[((nb*16 + kt)*64 + lane)*8 + j]  holds  B[k][n]
//   with n = nb*16 + (lane&15), k = kt*32 + (lane>>4)*8 + j.
__global__ void prep_bpack(const float* __restrict__ W, unsigned short* __restrict__ Bpack) {
  const int tid = blockIdx.x * blockDim.x + threadIdx.x;   // 262144 threads
  const int n = tid & 511, k = tid >> 9;
  const float w = W[(size_t)k * DD + n];                   // coalesced read
  const int nb = n >> 4, lo = n & 15;
  const int kt = k >> 5, hi = (k >> 3) & 3, j = k & 7;
  const int lane = hi * 16 + lo;
  Bpack[(((size_t)(nb * 16 + kt)) * 64 + lane) * 8 + j] = f2bf(w);
}

// Persistent producer/consumer fused kernel, 64-arch-VGPR-disciplined.
// Grid = 256 (1 block/CU). Waves 0-7 = PRODUCERS (load x, LN+relu, write bf16
// h and x into double-buffered LDS); waves 8-15 = CONSUMERS (GEMM vs Bpack
// with a DEPTH-2 pinned B ring — 32 VGPRs, fits the compiler's 64-reg arch
// budget, unlike R15's depth-3 which spilled). One lgkmcnt-only barrier per
// tile; producer HBM reads overlap consumer L2 loads + HBM stores.
__global__ __launch_bounds__(THREADS, 4)
void fused_ln_gemm(const float* __restrict__ x, const float* __restrict__ lns,
                   const float* __restrict__ lnb, const unsigned short* __restrict__ Bpack,
                   const float* __restrict__ bias, float* __restrict__ out) {
  __shared__ unsigned short Alds[2][BM * 512];   // 2 x 32 KB, h bf16, XOR-swizzled
  __shared__ unsigned short Xlds[2][BM * 512];   // 2 x 32 KB, x bf16, XOR-swizzled

  const int t = threadIdx.x;
  const long base = (long)blockIdx.x * (BM * TILES);
  const bool producer = (t < 512);

  if (producer) {
    // ================= PRODUCER: LN + relu into buf[(it+1)&1] ==========
    const int r = t >> 4, g = t & 15;          // 16 threads/row, 32 rows
    const unsigned abyte = (unsigned)(r * 1024 + g * 8) ^ (unsigned)((r & 7) << 4);

    #pragma unroll 1
    for (int it = -1; it + 1 < TILES; ++it) {
      const long trow = base + (long)(it + 1) * BM;
      const int buf = (it + 1) & 1;
      const float* xr = x + (trow + r) * DD + g * 4;
      float4 v[8];
      float s = 0.f, s2 = 0.f;
      #pragma unroll
      for (int i = 0; i < 8; ++i) {
        v[i] = *(const float4*)(xr + i * 64);
        s  += (v[i].x + v[i].y) + (v[i].z + v[i].w);
        s2 += v[i].x * v[i].x + v[i].y * v[i].y + v[i].z * v[i].z + v[i].w * v[i].w;
      }
      #pragma unroll
      for (int m = 1; m < 16; m <<= 1) {       // 16-lane group reduce
        s  += __shfl_xor(s,  m, 64);
        s2 += __shfl_xor(s2, m, 64);
      }
      const float mu   = s * (1.f / 512.f);
      const float var  = fmaxf(s2 * (1.f / 512.f) - mu * mu, 0.f);
      const float rstd = rsqrtf(var + 1e-6f);
      #pragma unroll
      for (int i = 0; i < 8; ++i) {
        const int c = g * 4 + i * 64;
        const float4 sc = *(const float4*)(lns + c);
        const float4 bi = *(const float4*)(lnb + c);
        ushort4 hu;
        hu.x = f2bf(fmaxf((v[i].x - mu) * rstd * sc.x + bi.x, 0.f));
        hu.y = f2bf(fmaxf((v[i].y - mu) * rstd * sc.y + bi.y, 0.f));
        hu.z = f2bf(fmaxf((v[i].z - mu) * rstd * sc.z + bi.z, 0.f));
        hu.w = f2bf(fmaxf((v[i].w - mu) * rstd * sc.w + bi.w, 0.f));
        ushort4 xu = { f2bf(v[i].x), f2bf(v[i].y), f2bf(v[i].z), f2bf(v[i].w) };
        const unsigned a = abyte ^ (unsigned)(i * 128);   // i*128 only touches bit7+
        *(ushort4*)((char*)&Alds[buf][0] + a) = hu;
        *(ushort4*)((char*)&Xlds[buf][0] + a) = xu;
      }
      asm volatile("s_waitcnt lgkmcnt(0)" ::: "memory");
      __builtin_amdgcn_s_barrier();
    }
    // final barrier (consumers finish tile TILES-1)
    asm volatile("s_waitcnt lgkmcnt(0)" ::: "memory");
    __builtin_amdgcn_s_barrier();
  } else {
    // ================= CONSUMER: GEMM + epilogue on buf[it&1] ==========
    const int ci = t - 512;
    const int lane = ci & 63, lo = lane & 15, hi = lane >> 4;
    const int cw = ci >> 6;                    // 0..7 -> 64-col strip
    const int col0 = cw * 64 + lo;
    const float bv[4] = { bias[col0], bias[col0 + 16], bias[col0 + 32], bias[col0 + 48] };

    const unsigned abase0 = (unsigned)(lo * 1024 + hi * 16);
    const unsigned abase1 = (unsigned)((16 + lo) * 1024 + hi * 16);
    const unsigned asw = (unsigned)((lo & 7) << 4);
    // B frag (nb = cw*4 + nt, kt): Bpack8 + (nb*16 + kt)*64 + lane
    const short8* bbase = (const short8*)Bpack + (size_t)cw * 4096 + lane;

    short8 rb[2][4];   // DEPTH-2 ring: 32 VGPRs, fits the 64-reg arch budget
#define LOADB(s_, kt)                                                        \
    { rb[s_][0] = bbase[(0 * 16 + (kt)) * 64];                               \
      rb[s_][1] = bbase[(1 * 16 + (kt)) * 64];                               \
      rb[s_][2] = bbase[(2 * 16 + (kt)) * 64];                               \
      rb[s_][3] = bbase[(3 * 16 + (kt)) * 64]; }

    // prefetch tile-0's first ring slot BEFORE waiting for producers
    LOADB(0, 0);
    __builtin_amdgcn_sched_barrier(0);

    // wait for producers' tile-0 LN
    __builtin_amdgcn_s_barrier();

    #pragma unroll 1
    for (int it = 0; it < TILES; ++it) {
      const long trow = base + (long)it * BM;
      const char* Ab = (const char*)&Alds[it & 1][0];
      const char* Xb = (const char*)&Xlds[it & 1][0];

      f32x4 acc0[4] = {};
      f32x4 acc1[4] = {};
      #pragma unroll
      for (int kt = 0; kt < 16; ++kt) {
        const int cur = kt & 1;
        if (kt + 1 < 16) LOADB((kt + 1) & 1, kt + 1);
        __builtin_amdgcn_sched_barrier(0);
        const short8 a0 = *(const short8*)(Ab + ((abase0 + (unsigned)kt * 64) ^ asw));
        const short8 a1 = *(const short8*)(Ab + ((abase1 + (unsigned)kt * 64) ^ asw));
        #pragma unroll
        for (int nt = 0; nt < 4; ++nt) {
          acc0[nt] = __builtin_amdgcn_mfma_f32_16x16x32_bf16(a0, rb[cur][nt], acc0[nt], 0, 0, 0);
          acc1[nt] = __builtin_amdgcn_mfma_f32_16x16x32_bf16(a1, rb[cur][nt], acc1[nt], 0, 0, 0);
        }
      }

      // epilogue: out = acc + x(Xlds) + bias   (stores never drained)
      #pragma unroll
      for (int q = 0; q < 4; ++q) {
        {
          const int rl = hi * 4 + q;
          const unsigned xb = (unsigned)(rl * 1024 + col0 * 2) ^ (unsigned)((rl & 7) << 4);
          float* o = out + (trow + rl) * DD + col0;
          #pragma unroll
          for (int nt = 0; nt < 4; ++nt)   // +nt*16 cols = ^ (nt<<5): bits 5-6 clear in base
            o[nt * 16] = acc0[nt][q] + bf2f(*(const unsigned short*)(Xb + (xb ^ (unsigned)(nt << 5)))) + bv[nt];
        }
        {
          const int rl = 16 + hi * 4 + q;
          const unsigned xb = (unsigned)(rl * 1024 + col0 * 2) ^ (unsigned)((rl & 7) << 4);
          float* o = out + (trow + rl) * DD + col0;
          #pragma unroll
          for (int nt = 0; nt < 4; ++nt)
            o[nt * 16] = acc1[nt][q] + bf2f(*(const unsigned short*)(Xb + (xb ^ (unsigned)(nt << 5)))) + bv[nt];
        }
      }

      // prefetch NEXT tile's first ring slot (B is tile-independent)
      if (it + 1 < TILES) {
        LOADB(0, 0);
        __builtin_amdgcn_sched_barrier(0);
      }

      asm volatile("s_waitcnt lgkmcnt(0)" ::: "memory");
      __builtin_amdgcn_s_barrier();
    }
#undef LOADB
  }
}

extern "C" void kernel_launch(void* const* d_in, const int* in_sizes, int n_in,
                              void* d_out, int out_size, void* d_ws, size_t ws_size,
                              hipStream_t stream) {
  const float* x    = (const float*)d_in[0];
  const float* lns  = (const float*)d_in[1];
  const float* lnb  = (const float*)d_in[2];
  const float* W    = (const float*)d_in[3];
  const float* bias = (const float*)d_in[4];
  float* out = (float*)d_out;
  unsigned short* Bpack = (unsigned short*)d_ws;   // 512KB scratch

  const int nrows = in_sizes[0] / DD;

  prep_bpack<<<DD * DD / 256, 256, 0, stream>>>(W, Bpack);
  fused_ln_gemm<<<nrows / (BM * TILES), THREADS, 0, stream>>>(x, lns, lnb, Bpack, bias, out);
}

// Round 18
// 480.051 us; speedup vs baseline: 2.5294x; 2.3194x over previous
//
#include <hip/hip_runtime.h>
#include <hip/hip_bf16.h>

#define DD 512
#define BM 32
#define TILES 32          // rows per block = 1024; grid = 256 (1 block/CU)
#define THREADS 1024

typedef __attribute__((ext_vector_type(8))) short short8;   // 8 bf16 (MFMA A/B frag)
typedef __attribute__((ext_vector_type(4))) float f32x4;    // MFMA C/D frag

__device__ __forceinline__ unsigned short f2bf(float f) {
  union { float f; unsigned u; } v; v.f = f;
  unsigned r = v.u + 0x7FFFu + ((v.u >> 16) & 1u);  // RNE
  return (unsigned short)(r >> 16);
}

// async global->LDS DMA, 16B per lane, wave-uniform LDS base + lane*16
__device__ __forceinline__ void gload16(const float* g, float* l) {
  __builtin_amdgcn_global_load_lds(
      (const __attribute__((address_space(1))) unsigned int*)g,
      (__attribute__((address_space(3))) unsigned int*)l, 16, 0, 0);
}

// Pack kernel (K x N fp32, row-major) into MFMA-fragment-major bf16:
//   Bpack[((nb*16 + kt)*64 + lane)*8 + j]  holds  B[k][n]
//   with n = nb*16 + (lane&15), k = kt*32 + (lane>>4)*8 + j.
__global__ void prep_bpack(const float* __restrict__ W, unsigned short* __restrict__ Bpack) {
  const int tid = blockIdx.x * blockDim.x + threadIdx.x;   // 262144 threads
  const int n = tid & 511, k = tid >> 9;
  const float w = W[(size_t)k * DD + n];                   // coalesced read
  const int nb = n >> 4, lo = n & 15;
  const int kt = k >> 5, hi = (k >> 3) & 3, j = k & 7;
  const int lane = hi * 16 + lo;
  Bpack[(((size_t)(nb * 16 + kt)) * 64 + lane) * 8 + j] = f2bf(w);
}

// Persistent async-staged fused kernel. x is DMA'd fp32 into double-buffered
// LDS (global_load_lds: no VGPR cost, no vmcnt(0) drain — counted waits).
// Wave w stages exactly the 2 rows it LN-reads -> own-wave vmcnt suffices.
// Residual read as exact fp32 from LDS in the epilogue.
__global__ __launch_bounds__(THREADS, 4)
void fused_ln_gemm(const float* __restrict__ x, const float* __restrict__ lns,
                   const float* __restrict__ lnb, const unsigned short* __restrict__ Bpack,
                   const float* __restrict__ bias, float* __restrict__ out) {
  __shared__ float Xf32[2][BM * DD];            // 2 x 64 KB, raw fp32 x (linear)
  __shared__ unsigned short Alds[BM * DD];      // 32 KB, h bf16, XOR-swizzled

  const int t = threadIdx.x;
  const int lane = t & 63, lo = lane & 15, hi = lane >> 4;
  const int w = t >> 6;                         // wave id 0..15 -> 32-col strip
  const int r = t >> 5, g = t & 31;             // LN: 32 threads/row, rows 2w,2w+1
  const long base = (long)blockIdx.x * (BM * TILES);

  const int col0 = w * 32 + lo;
  const float bv0 = bias[col0];
  const float bv1 = bias[col0 + 16];

  const unsigned abase0 = (unsigned)(lo * 1024 + hi * 16);
  const unsigned abase1 = (unsigned)((16 + lo) * 1024 + hi * 16);
  const unsigned asw = (unsigned)((lo & 7) << 4);
  // B frag (nb = w*2 + nt, kt): Bpack8 + (nb*16 + kt)*64 + lane  (16B units)
  const short8* bbase = (const short8*)Bpack + (size_t)w * 2048 + lane;

  // ---- prologue: DMA tile 0 (wave w stages its own rows 2w,2w+1) -------
  {
    const float* src = x + base * DD;
    #pragma unroll
    for (int rr = 0; rr < 2; ++rr)
      #pragma unroll
      for (int c = 0; c < 2; ++c)
        gload16(src + (2 * w + rr) * DD + c * 256 + lane * 4,
                &Xf32[0][(2 * w + rr) * DD + c * 256]);
  }
  asm volatile("s_waitcnt vmcnt(0)" ::: "memory");

  #pragma unroll 1
  for (int it = 0; it < TILES; ++it) {
    const long trow = base + (long)it * BM;
    const int cur = it & 1;
    float* Xc = &Xf32[cur][0];

    // counted wait: the 16 newest outstanding VMEM ops are last tile's
    // stores; waiting to <=16 retires this tile's 4 G-loads. Never drains.
    if (it) asm volatile("s_waitcnt vmcnt(16)" ::: "memory");

    // ---- issue DMA for tile it+1 into the other buffer ----------------
    if (it + 1 < TILES) {
      const float* src = x + (trow + BM) * DD;
      float* dst = &Xf32[cur ^ 1][0];
      #pragma unroll
      for (int rr = 0; rr < 2; ++rr)
        #pragma unroll
        for (int c = 0; c < 2; ++c)
          gload16(src + (2 * w + rr) * DD + c * 256 + lane * 4,
                  dst + (2 * w + rr) * DD + c * 256);
    }

    // ---- LN + relu from Xf32[cur] (own-wave rows), write Alds ----------
    {
      float4 v[4];
      float s = 0.f, s2 = 0.f;
      #pragma unroll
      for (int i = 0; i < 4; ++i) {
        v[i] = *(const float4*)(Xc + r * DD + g * 4 + i * 128);
        s  += (v[i].x + v[i].y) + (v[i].z + v[i].w);
        s2 += v[i].x * v[i].x + v[i].y * v[i].y + v[i].z * v[i].z + v[i].w * v[i].w;
      }
      #pragma unroll
      for (int m = 1; m < 32; m <<= 1) {   // 32-lane group reduce
        s  += __shfl_xor(s,  m, 64);
        s2 += __shfl_xor(s2, m, 64);
      }
      const float mu   = s * (1.f / 512.f);
      const float var  = fmaxf(s2 * (1.f / 512.f) - mu * mu, 0.f);
      const float rstd = rsqrtf(var + 1e-6f);
      #pragma unroll
      for (int i = 0; i < 4; ++i) {
        const int c = g * 4 + i * 128;
        const float4 sc = *(const float4*)(lns + c);
        const float4 bi = *(const float4*)(lnb + c);
        ushort4 hu;
        hu.x = f2bf(fmaxf((v[i].x - mu) * rstd * sc.x + bi.x, 0.f));
        hu.y = f2bf(fmaxf((v[i].y - mu) * rstd * sc.y + bi.y, 0.f));
        hu.z = f2bf(fmaxf((v[i].z - mu) * rstd * sc.z + bi.z, 0.f));
        hu.w = f2bf(fmaxf((v[i].w - mu) * rstd * sc.w + bi.w, 0.f));
        const unsigned a = (unsigned)(r * 1024 + c * 2) ^ (unsigned)((r & 7) << 4);
        *(ushort4*)((char*)Alds + a) = hu;
      }
    }
    asm volatile("s_waitcnt lgkmcnt(0)" ::: "memory");
    __builtin_amdgcn_s_barrier();          // Alds + all waves' Xf32[cur] ready

    // ---- GEMM: depth-2 pinned B ring (16 VGPRs) ------------------------
    f32x4 acc00 = {}, acc01 = {}, acc10 = {}, acc11 = {};
    {
      short8 rb[2][2];
#define LOADB(s_, kt)                                                        \
      { rb[s_][0] = bbase[(0 * 16 + (kt)) * 64];                             \
        rb[s_][1] = bbase[(1 * 16 + (kt)) * 64]; }
      LOADB(0, 0);
      __builtin_amdgcn_sched_barrier(0);
      #pragma unroll
      for (int kt = 0; kt < 16; ++kt) {
        const int c2 = kt & 1;
        if (kt + 1 < 16) LOADB((kt + 1) & 1, kt + 1);
        __builtin_amdgcn_sched_barrier(0);
        const short8 a0 = *(const short8*)((const char*)Alds + ((abase0 + (unsigned)kt * 64) ^ asw));
        const short8 a1 = *(const short8*)((const char*)Alds + ((abase1 + (unsigned)kt * 64) ^ asw));
        acc00 = __builtin_amdgcn_mfma_f32_16x16x32_bf16(a0, rb[c2][0], acc00, 0, 0, 0);
        acc01 = __builtin_amdgcn_mfma_f32_16x16x32_bf16(a0, rb[c2][1], acc01, 0, 0, 0);
        acc10 = __builtin_amdgcn_mfma_f32_16x16x32_bf16(a1, rb[c2][0], acc10, 0, 0, 0);
        acc11 = __builtin_amdgcn_mfma_f32_16x16x32_bf16(a1, rb[c2][1], acc11, 0, 0, 0);
      }
#undef LOADB
    }

    // ---- epilogue: out = acc + x(fp32, LDS) + bias; stores in flight ---
    {
      float* oc = out + (trow + hi * 4) * DD + col0;
      #pragma unroll
      for (int m = 0; m < 2; ++m) {
        #pragma unroll
        for (int q = 0; q < 4; ++q) {
          const int rl = m * 16 + hi * 4 + q;
          const float xv0 = Xc[rl * DD + col0];
          const float xv1 = Xc[rl * DD + col0 + 16];
          float* o = oc + (m * 16 + q) * DD;
          o[0]  = ((m == 0) ? ((q == 0) ? acc00[0] : (q == 1) ? acc00[1] : (q == 2) ? acc00[2] : acc00[3])
                            : ((q == 0) ? acc10[0] : (q == 1) ? acc10[1] : (q == 2) ? acc10[2] : acc10[3])) + xv0 + bv0;
          o[16] = ((m == 0) ? ((q == 0) ? acc01[0] : (q == 1) ? acc01[1] : (q == 2) ? acc01[2] : acc01[3])
                            : ((q == 0) ? acc11[0] : (q == 1) ? acc11[1] : (q == 2) ? acc11[2] : acc11[3])) + xv1 + bv1;
        }
      }
    }
    asm volatile("s_waitcnt lgkmcnt(0)" ::: "memory");   // LDS reads done
    __builtin_amdgcn_s_barrier();          // Xf32[cur]/Alds free for reuse
  }
}

extern "C" void kernel_launch(void* const* d_in, const int* in_sizes, int n_in,
                              void* d_out, int out_size, void* d_ws, size_t ws_size,
                              hipStream_t stream) {
  const float* x    = (const float*)d_in[0];
  const float* lns  = (const float*)d_in[1];
  const float* lnb  = (const float*)d_in[2];
  const float* W    = (const float*)d_in[3];
  const float* bias = (const float*)d_in[4];
  float* out = (float*)d_out;
  unsigned short* Bpack = (unsigned short*)d_ws;   // 512KB scratch

  const int nrows = in_sizes[0] / DD;

  prep_bpack<<<DD * DD / 256, 256, 0, stream>>>(W, Bpack);
  fused_ln_gemm<<<nrows / (BM * TILES), THREADS, 0, stream>>>(x, lns, lnb, Bpack, bias, out);
}